// Round 10
// baseline (30.716 us; speedup 1.0000x reference)
//
#include <hip/hip_runtime.h>
#include <hip/hip_bf16.h>

#define NQ 8
#define DIM 256
#define NL 3
#define BATCH 16384

using bf16x8 = __attribute__((ext_vector_type(8))) short;
using f32x4  = __attribute__((ext_vector_type(4))) float;

static __device__ __forceinline__ unsigned short f2bf(float f) {
    union { __hip_bfloat16 b; unsigned short u; } cv;
    cv.b = __float2bfloat16(f);
    return cv.u;
}

#define RYPAIR(c0, c1)                                                  \
    {                                                                   \
        float lr = re[c0], li = im[c0], hr = re[c1], hi = im[c1];       \
        re[c0] = cc * lr - s * hr;  im[c0] = cc * li - s * hi;          \
        re[c1] = s * lr + cc * hr;  im[c1] = s * li + cc * hi;          \
    }

// Shared gate sequence (r8-verified, byte-identical).
#define RUN_LAYERS()                                                              \
    for (int layer = 0; layer < NL; ++layer) {                                    \
        _Pragma("unroll")                                                         \
        for (int q = 0; q < NQ; ++q) {                                            \
            float a = 0.5f * theta[layer * NQ + q];                               \
            float s, cc; sincosf(a, &s, &cc);                                     \
            const int mask = 1 << (7 - q);                                        \
            if (mask == 128)      { RYPAIR(0, 2); RYPAIR(1, 3); }                 \
            else if (mask == 64)  { RYPAIR(0, 1); RYPAIR(2, 3); }                 \
            else {                                                                \
                _Pragma("unroll")                                                 \
                for (int c = 0; c < 4; ++c) {                                     \
                    float pr = __shfl_xor(re[c], mask);                           \
                    float pi = __shfl_xor(im[c], mask);                           \
                    if (lane & mask) { re[c] = s * pr + cc * re[c]; im[c] = s * pi + cc * im[c]; } \
                    else             { re[c] = cc * re[c] - s * pr; im[c] = cc * im[c] - s * pi; } \
                }                                                                 \
            }                                                                     \
        }                                                                         \
        _Pragma("unroll")                                                         \
        for (int i = 0; i < NQ; ++i) {                                            \
            int t2 = tgt[i];                                                      \
            if (t2 == i) continue;                                                \
            int cmask = 1 << (7 - i);                                             \
            int tmask = 1 << (7 - t2);                                            \
            if (tmask == 128) {                                                   \
                int j0 = lane, j1 = 64 + lane, j2 = 128 + lane, j3 = 192 + lane;  \
                bool k0 = (j0 & cmask), k1 = (j1 & cmask), k2 = (j2 & cmask), k3 = (j3 & cmask); \
                float n0r = k0 ? re[2] : re[0], n0i = k0 ? im[2] : im[0];         \
                float n1r = k1 ? re[3] : re[1], n1i = k1 ? im[3] : im[1];         \
                float n2r = k2 ? re[0] : re[2], n2i = k2 ? im[0] : im[2];         \
                float n3r = k3 ? re[1] : re[3], n3i = k3 ? im[1] : im[3];         \
                re[0] = n0r; im[0] = n0i; re[1] = n1r; im[1] = n1i;               \
                re[2] = n2r; im[2] = n2i; re[3] = n3r; im[3] = n3i;               \
            } else if (tmask == 64) {                                             \
                int j0 = lane, j1 = 64 + lane, j2 = 128 + lane, j3 = 192 + lane;  \
                bool k0 = (j0 & cmask), k1 = (j1 & cmask), k2 = (j2 & cmask), k3 = (j3 & cmask); \
                float n0r = k0 ? re[1] : re[0], n0i = k0 ? im[1] : im[0];         \
                float n1r = k1 ? re[0] : re[1], n1i = k1 ? im[0] : im[1];         \
                float n2r = k2 ? re[3] : re[2], n2i = k2 ? im[3] : im[2];         \
                float n3r = k3 ? re[2] : re[3], n3i = k3 ? im[2] : im[3];         \
                re[0] = n0r; im[0] = n0i; re[1] = n1r; im[1] = n1i;               \
                re[2] = n2r; im[2] = n2i; re[3] = n3r; im[3] = n3i;               \
            } else {                                                              \
                _Pragma("unroll")                                                 \
                for (int c = 0; c < 4; ++c) {                                     \
                    int j = c * 64 + lane;                                        \
                    float pr = __shfl_xor(re[c], tmask);                          \
                    float pi = __shfl_xor(im[c], tmask);                          \
                    bool take = (j & cmask) != 0;                                 \
                    re[c] = take ? pr : re[c];                                    \
                    im[c] = take ? pi : im[c];                                    \
                }                                                                 \
            }                                                                     \
        }                                                                         \
        _Pragma("unroll")                                                         \
        for (int q = 0; q < NQ; ++q) {                                            \
            float a = 0.5f * omega[layer * NQ + q];                               \
            float sa, ca; sincosf(a, &sa, &ca);                                   \
            const int mask = 1 << (7 - q);                                        \
            _Pragma("unroll")                                                     \
            for (int c = 0; c < 4; ++c) {                                         \
                int j = c * 64 + lane;                                            \
                float sb = (j & mask) ? sa : -sa;                                 \
                float r2 = re[c] * ca - im[c] * sb;                               \
                float i2 = re[c] * sb + im[c] * ca;                               \
                re[c] = r2; im[c] = i2;                                           \
            }                                                                     \
        }                                                                         \
    }

#define ARGMAX_TGT()                                                    \
    int tgt[NQ];                                                        \
    _Pragma("unroll")                                                   \
    for (int i = 0; i < NQ; ++i) {                                      \
        const float* row = attn_w + i * NQ;                             \
        int best = 0; float bv = row[0];                                \
        _Pragma("unroll")                                               \
        for (int t2 = 1; t2 < NQ; ++t2) {                               \
            float v = row[t2];                                          \
            if (v > bv) { bv = v; best = t2; }                          \
        }                                                               \
        tgt[i] = best;                                                  \
    }

// ---------------------------------------------------------------------------
// Kernel 1 (r9-verified, unchanged): build B in MFMA-fragment order.
//   ws_idx(k, n) = ((k>>5)*32 + (n>>4))*64*8 + (((k>>3)&3)*16 + (n&15))*8 + (k&7)
// Slot->k map k = ks*32 + g*8 + e used on BOTH operands -> internal order cancels.
// ---------------------------------------------------------------------------
__global__ __launch_bounds__(256) void build_B_kernel(
    const float* __restrict__ theta, const float* __restrict__ omega,
    const float* __restrict__ attn_w, unsigned short* __restrict__ Bf)
{
    const int lane = threadIdx.x & 63;
    const int k = blockIdx.x * 4 + (threadIdx.x >> 6);

    ARGMAX_TGT();

    float re[4], im[4];
    #pragma unroll
    for (int c = 0; c < 4; ++c) {
        re[c] = (c * 64 + lane == k) ? 1.0f : 0.0f;
        im[c] = 0.0f;
    }

    RUN_LAYERS();

    const int kbase = (k >> 5) * 32;
    const int lg16  = ((k >> 3) & 3) * 16;
    const int e     = k & 7;
    #pragma unroll
    for (int c = 0; c < 4; ++c) {
        int j  = c * 64 + lane;
        int n0 = 2 * j, n1 = 2 * j + 1;
        size_t o0 = ((size_t)(kbase + (n0 >> 4)) * 64 + lg16 + (n0 & 15)) * 8 + e;
        size_t o1 = ((size_t)(kbase + (n1 >> 4)) * 64 + lg16 + (n1 & 15)) * 8 + e;
        Bf[o0] = f2bf(im[c]);   // even n: imag (H-IMRE)
        Bf[o1] = f2bf(re[c]);   // odd  n: real
    }
}

// ---------------------------------------------------------------------------
// Kernel 2: out[b][n] = sum_k S[b][k]*B[k][n]  (M=16384, N=512, K=256)
// ROUND 10: 256-thr blocks, tile M=32 x N=256; grid 1024 (4 blk/CU, 16 w/CU).
// acc = 2x4 f32x4 = 32 VGPR; launch_bounds(256,4) caps VGPR at 128 (no spill).
// MFMA operands SWAPPED: D' = mfma(bfrag, afrag) = D[n][b] tile
// (col=lane&15=b, row=(lane>>4)*4+r = n, m89-verified) -> each lane's 4 regs
// are 4 consecutive n -> one packed 8B store; 16 stores/thread (was 64x2B).
// ---------------------------------------------------------------------------
__global__ __launch_bounds__(256, 4) void gemm_kernel(
    const float* __restrict__ x, const unsigned short* __restrict__ Bf,
    unsigned short* __restrict__ out)
{
    __shared__ unsigned short A_lds[32][264];   // 32 x 256 bf16, +8 pad (16.9 KB)
    __shared__ float trig[32][NQ][2];
    const int t = threadIdx.x;
    const int mb = blockIdx.x >> 1;             // M-tile (32 rows)
    const int nh = blockIdx.x & 1;              // N-half (256 cols)
    const int b0 = mb * 32;

    // sincos: one (sample, qubit) per thread (32 x 8 = 256)
    {
        int b = t >> 3, q = t & 7;
        float a = 0.5f * x[(size_t)(b0 + b) * NQ + q];
        float s, c; sincosf(a, &s, &c);
        trig[b][q][0] = c; trig[b][q][1] = s;
    }
    __syncthreads();

    // product state S[b][j]: 8 threads per sample, 32 j's per thread (r9-verified)
    {
        int b = t >> 3;
        int j0 = (t & 7) * 32;
        float cq[NQ], sq[NQ];
        #pragma unroll
        for (int q = 0; q < NQ; ++q) { cq[q] = trig[b][q][0]; sq[q] = trig[b][q][1]; }
        float hi3 = (((j0 >> 7) & 1) ? sq[0] : cq[0]) *
                    (((j0 >> 6) & 1) ? sq[1] : cq[1]) *
                    (((j0 >> 5) & 1) ? sq[2] : cq[2]);
        float t3[8];
        #pragma unroll
        for (int h = 0; h < 8; ++h)
            t3[h] = ((h & 4) ? sq[3] : cq[3]) * ((h & 2) ? sq[4] : cq[4]) * ((h & 1) ? sq[5] : cq[5]);
        float t2v[4];
        #pragma unroll
        for (int v2 = 0; v2 < 4; ++v2)
            t2v[v2] = ((v2 & 2) ? sq[6] : cq[6]) * ((v2 & 1) ? sq[7] : cq[7]);
        #pragma unroll
        for (int i = 0; i < 32; i += 2) {
            float v0 = hi3 * t3[i >> 2] * t2v[i & 3];
            float v1 = hi3 * t3[(i + 1) >> 2] * t2v[(i + 1) & 3];
            unsigned int pack = (unsigned int)f2bf(v0) | ((unsigned int)f2bf(v1) << 16);
            *(unsigned int*)&A_lds[b][j0 + i] = pack;
        }
    }
    __syncthreads();

    // MFMA main loop
    const int w = t >> 6;                       // wave -> 4 ntiles
    const int l = t & 63;
    const int lrow = l & 15, lgrp = l >> 4;
    f32x4 acc[2][4];
    #pragma unroll
    for (int m = 0; m < 2; ++m)
        #pragma unroll
        for (int nt = 0; nt < 4; ++nt)
            acc[m][nt] = (f32x4){0.f, 0.f, 0.f, 0.f};

    #pragma unroll 2
    for (int ks = 0; ks < 8; ++ks) {
        bf16x8 bfrag[4];
        #pragma unroll
        for (int nt = 0; nt < 4; ++nt)
            bfrag[nt] = *(const bf16x8*)&Bf[((size_t)(ks * 32 + nh * 16 + w * 4 + nt) * 64 + l) * 8];
        bf16x8 afrag[2];
        #pragma unroll
        for (int m = 0; m < 2; ++m)
            afrag[m] = *(const bf16x8*)&A_lds[m * 16 + lrow][ks * 32 + lgrp * 8];
        #pragma unroll
        for (int m = 0; m < 2; ++m)
            #pragma unroll
            for (int nt = 0; nt < 4; ++nt)
                acc[m][nt] = __builtin_amdgcn_mfma_f32_16x16x32_bf16(
                    bfrag[nt], afrag[m], acc[m][nt], 0, 0, 0);   // SWAPPED: D[n][b]
    }

    // epilogue: lane -> batch b0+m*16+lrow, n = ntile*16 + lgrp*4 + r (r=0..3)
    #pragma unroll
    for (int m = 0; m < 2; ++m)
        #pragma unroll
        for (int nt = 0; nt < 4; ++nt) {
            int row = b0 + m * 16 + lrow;
            int n = (nh * 16 + w * 4 + nt) * 16 + lgrp * 4;
            unsigned int lo = (unsigned int)f2bf(acc[m][nt][0]) | ((unsigned int)f2bf(acc[m][nt][1]) << 16);
            unsigned int hi = (unsigned int)f2bf(acc[m][nt][2]) | ((unsigned int)f2bf(acc[m][nt][3]) << 16);
            uint2 v; v.x = lo; v.y = hi;
            *(uint2*)&out[(size_t)row * 512 + n] = v;
        }
}

// ---------------------------------------------------------------------------
// Fallback: r8's verified direct simulation (used only if ws_size < 256 KB).
// ---------------------------------------------------------------------------
__global__ __launch_bounds__(256) void sim_kernel(
    const float* __restrict__ x, const float* __restrict__ theta,
    const float* __restrict__ omega, const float* __restrict__ attn_w,
    unsigned short* __restrict__ out)
{
    const int lane = threadIdx.x & 63;
    const int b = blockIdx.x * 4 + (threadIdx.x >> 6);

    ARGMAX_TGT();

    float cq[NQ], sq[NQ];
    #pragma unroll
    for (int q = 0; q < NQ; ++q) {
        float a = 0.5f * x[(size_t)b * NQ + q];
        sincosf(a, &sq[q], &cq[q]);
    }
    float re[4], im[4];
    #pragma unroll
    for (int c = 0; c < 4; ++c) {
        int j = c * 64 + lane;
        float v = 1.0f;
        #pragma unroll
        for (int q = 0; q < NQ; ++q)
            v *= ((j >> (7 - q)) & 1) ? sq[q] : cq[q];
        re[c] = v; im[c] = 0.0f;
    }

    RUN_LAYERS();

    #pragma unroll
    for (int c = 0; c < 4; ++c) {
        size_t elem = (size_t)b * DIM + c * 64 + lane;
        unsigned int pack = (unsigned int)f2bf(im[c]) | ((unsigned int)f2bf(re[c]) << 16);
        *(unsigned int*)&out[elem * 2] = pack;
    }
}

extern "C" void kernel_launch(void* const* d_in, const int* in_sizes, int n_in,
                              void* d_out, int out_size, void* d_ws, size_t ws_size,
                              hipStream_t stream) {
    const float* x      = (const float*)d_in[0];
    const float* theta  = (const float*)d_in[1];
    const float* omega  = (const float*)d_in[2];
    const float* attn_w = (const float*)d_in[3];

    const size_t B_BYTES = (size_t)DIM * 512 * 2;   // 256 KB fragment-ordered B
    if (ws_size >= B_BYTES) {
        unsigned short* Bf = (unsigned short*)d_ws;
        build_B_kernel<<<DIM / 4, 256, 0, stream>>>(theta, omega, attn_w, Bf);
        gemm_kernel<<<(BATCH / 32) * 2, 256, 0, stream>>>(x, Bf, (unsigned short*)d_out);
    } else {
        sim_kernel<<<BATCH / 4, 256, 0, stream>>>(x, theta, omega, attn_w,
                                                  (unsigned short*)d_out);
    }
}

// Round 11
// 24.039 us; speedup vs baseline: 1.2778x; 1.2778x over previous
//
#include <hip/hip_runtime.h>
#include <hip/hip_bf16.h>

#define NQ 8
#define DIM 256
#define NL 3
#define BATCH 16384

using bf16x8 = __attribute__((ext_vector_type(8))) short;
using f32x4  = __attribute__((ext_vector_type(4))) float;

static __device__ __forceinline__ unsigned short f2bf(float f) {
    union { __hip_bfloat16 b; unsigned short u; } cv;
    cv.b = __float2bfloat16(f);
    return cv.u;
}

#define RYPAIR(c0, c1)                                                  \
    {                                                                   \
        float lr = re[c0], li = im[c0], hr = re[c1], hi = im[c1];       \
        re[c0] = cc * lr - s * hr;  im[c0] = cc * li - s * hi;          \
        re[c1] = s * lr + cc * hr;  im[c1] = s * li + cc * hi;          \
    }

// ---------------------------------------------------------------------------
// Kernel 1: build B in MFMA-fragment order (r9-verified layout/store).
// ROUND 11: block-uniform work (48 sincos pairs + 8 argmax rows) computed
// ONCE per block by parallel threads into LDS; the gate chain reads broadcast
// LDS scalars instead of inlining ~40-inst sincosf chains per gate.
// Values bit-identical to r9 (same sincosf outputs feed same sums).
//   ws_idx(k, n) = ((k>>5)*32 + (n>>4))*64*8 + (((k>>3)&3)*16 + (n&15))*8 + (k&7)
// Slot->k map k = ks*32 + g*8 + e used on BOTH gemm operands -> cancels.
// ---------------------------------------------------------------------------
__global__ __launch_bounds__(256) void build_B_kernel(
    const float* __restrict__ theta, const float* __restrict__ omega,
    const float* __restrict__ attn_w, unsigned short* __restrict__ Bf)
{
    __shared__ float thc[NL * NQ], ths[NL * NQ];   // cos/sin of theta/2
    __shared__ float omc[NL * NQ], oms[NL * NQ];   // cos/sin of omega/2
    __shared__ int   tgt_l[NQ];

    const int t = threadIdx.x;
    if (t < NL * NQ) {
        float s, c; sincosf(0.5f * theta[t], &s, &c);
        ths[t] = s; thc[t] = c;
    } else if (t < 2 * NL * NQ) {
        int i = t - NL * NQ;
        float s, c; sincosf(0.5f * omega[i], &s, &c);
        oms[i] = s; omc[i] = c;
    } else if (t < 2 * NL * NQ + NQ) {
        int i = t - 2 * NL * NQ;
        const float* row = attn_w + i * NQ;
        int best = 0; float bv = row[0];
        #pragma unroll
        for (int t2 = 1; t2 < NQ; ++t2) {
            float v = row[t2];
            if (v > bv) { bv = v; best = t2; }   // strict >: first-max tie rule
        }
        tgt_l[i] = best;
    }
    __syncthreads();

    const int lane = t & 63;
    const int k = blockIdx.x * 4 + (t >> 6);   // basis state 0..255

    float re[4], im[4];
    #pragma unroll
    for (int c = 0; c < 4; ++c) {
        re[c] = (c * 64 + lane == k) ? 1.0f : 0.0f;
        im[c] = 0.0f;
    }

    for (int layer = 0; layer < NL; ++layer) {
        // ---- RY(theta[layer][q]) ----
        #pragma unroll
        for (int q = 0; q < NQ; ++q) {
            float s = ths[layer * NQ + q], cc = thc[layer * NQ + q];
            const int mask = 1 << (7 - q);
            if (mask == 128)      { RYPAIR(0, 2); RYPAIR(1, 3); }
            else if (mask == 64)  { RYPAIR(0, 1); RYPAIR(2, 3); }
            else {
                #pragma unroll
                for (int c = 0; c < 4; ++c) {
                    float pr = __shfl_xor(re[c], mask);
                    float pi = __shfl_xor(im[c], mask);
                    if (lane & mask) { re[c] = s * pr + cc * re[c]; im[c] = s * pi + cc * im[c]; }
                    else             { re[c] = cc * re[c] - s * pr; im[c] = cc * im[c] - s * pi; }
                }
            }
        }
        // ---- CNOT(control=i, target=tgt[i]); identity if equal ----
        #pragma unroll
        for (int i = 0; i < NQ; ++i) {
            int t2 = tgt_l[i];
            if (t2 == i) continue;                 // block-uniform branch
            int cmask = 1 << (7 - i);
            int tmask = 1 << (7 - t2);
            if (tmask == 128) {
                int j0 = lane, j1 = 64 + lane, j2 = 128 + lane, j3 = 192 + lane;
                bool k0 = (j0 & cmask), k1 = (j1 & cmask), k2 = (j2 & cmask), k3 = (j3 & cmask);
                float n0r = k0 ? re[2] : re[0], n0i = k0 ? im[2] : im[0];
                float n1r = k1 ? re[3] : re[1], n1i = k1 ? im[3] : im[1];
                float n2r = k2 ? re[0] : re[2], n2i = k2 ? im[0] : im[2];
                float n3r = k3 ? re[1] : re[3], n3i = k3 ? im[1] : im[3];
                re[0] = n0r; im[0] = n0i; re[1] = n1r; im[1] = n1i;
                re[2] = n2r; im[2] = n2i; re[3] = n3r; im[3] = n3i;
            } else if (tmask == 64) {
                int j0 = lane, j1 = 64 + lane, j2 = 128 + lane, j3 = 192 + lane;
                bool k0 = (j0 & cmask), k1 = (j1 & cmask), k2 = (j2 & cmask), k3 = (j3 & cmask);
                float n0r = k0 ? re[1] : re[0], n0i = k0 ? im[1] : im[0];
                float n1r = k1 ? re[0] : re[1], n1i = k1 ? im[0] : im[1];
                float n2r = k2 ? re[3] : re[2], n2i = k2 ? im[3] : im[2];
                float n3r = k3 ? re[2] : re[3], n3i = k3 ? im[2] : im[3];
                re[0] = n0r; im[0] = n0i; re[1] = n1r; im[1] = n1i;
                re[2] = n2r; im[2] = n2i; re[3] = n3r; im[3] = n3i;
            } else {
                #pragma unroll
                for (int c = 0; c < 4; ++c) {
                    int j = c * 64 + lane;
                    float pr = __shfl_xor(re[c], tmask);
                    float pi = __shfl_xor(im[c], tmask);
                    bool take = (j & cmask) != 0;
                    re[c] = take ? pr : re[c];
                    im[c] = take ? pi : im[c];
                }
            }
        }
        // ---- RZ(omega[layer][q]) ----
        #pragma unroll
        for (int q = 0; q < NQ; ++q) {
            float sa = oms[layer * NQ + q], ca = omc[layer * NQ + q];
            const int mask = 1 << (7 - q);
            #pragma unroll
            for (int c = 0; c < 4; ++c) {
                int j = c * 64 + lane;
                float sb = (j & mask) ? sa : -sa;
                float r2 = re[c] * ca - im[c] * sb;
                float i2 = re[c] * sb + im[c] * ca;
                re[c] = r2; im[c] = i2;
            }
        }
    }

    const int kbase = (k >> 5) * 32;
    const int lg16  = ((k >> 3) & 3) * 16;
    const int e     = k & 7;
    #pragma unroll
    for (int c = 0; c < 4; ++c) {
        int j  = c * 64 + lane;
        int n0 = 2 * j, n1 = 2 * j + 1;
        size_t o0 = ((size_t)(kbase + (n0 >> 4)) * 64 + lg16 + (n0 & 15)) * 8 + e;
        size_t o1 = ((size_t)(kbase + (n1 >> 4)) * 64 + lg16 + (n1 & 15)) * 8 + e;
        Bf[o0] = f2bf(im[c]);   // even n: imag (H-IMRE)
        Bf[o1] = f2bf(re[c]);   // odd  n: real
    }
}

// ---------------------------------------------------------------------------
// Kernel 2 (r9 version verbatim — measured best: 29.3 vs r10's 30.7):
// out[b][n] = sum_k S[b][k]*B[k][n]  (M=16384, N=512, K=256)
// 512 threads = 8 waves, M_TILE=64/block, grid=256.
// ---------------------------------------------------------------------------
__global__ __launch_bounds__(512) void gemm_kernel(
    const float* __restrict__ x, const unsigned short* __restrict__ Bf,
    unsigned short* __restrict__ out)
{
    __shared__ unsigned short A_lds[64][264];   // 64 x 256 bf16, +8 pad
    __shared__ float trig[64][NQ][2];
    const int t = threadIdx.x;
    const int b0 = blockIdx.x * 64;

    {
        int b = t >> 3, q = t & 7;
        float a = 0.5f * x[(size_t)(b0 + b) * NQ + q];
        float s, c; sincosf(a, &s, &c);
        trig[b][q][0] = c; trig[b][q][1] = s;
    }
    __syncthreads();

    {
        int b = t >> 3;
        int j0 = (t & 7) * 32;
        float cq[NQ], sq[NQ];
        #pragma unroll
        for (int q = 0; q < NQ; ++q) { cq[q] = trig[b][q][0]; sq[q] = trig[b][q][1]; }
        float hi3 = (((j0 >> 7) & 1) ? sq[0] : cq[0]) *
                    (((j0 >> 6) & 1) ? sq[1] : cq[1]) *
                    (((j0 >> 5) & 1) ? sq[2] : cq[2]);
        float t3[8];
        #pragma unroll
        for (int h = 0; h < 8; ++h)
            t3[h] = ((h & 4) ? sq[3] : cq[3]) * ((h & 2) ? sq[4] : cq[4]) * ((h & 1) ? sq[5] : cq[5]);
        float t2v[4];
        #pragma unroll
        for (int v2 = 0; v2 < 4; ++v2)
            t2v[v2] = ((v2 & 2) ? sq[6] : cq[6]) * ((v2 & 1) ? sq[7] : cq[7]);
        #pragma unroll
        for (int i = 0; i < 32; i += 2) {
            float v0 = hi3 * t3[i >> 2] * t2v[i & 3];
            float v1 = hi3 * t3[(i + 1) >> 2] * t2v[(i + 1) & 3];
            unsigned int pack = (unsigned int)f2bf(v0) | ((unsigned int)f2bf(v1) << 16);
            *(unsigned int*)&A_lds[b][j0 + i] = pack;
        }
    }
    __syncthreads();

    const int w = t >> 6;
    const int l = t & 63;
    const int lrow = l & 15, lgrp = l >> 4;
    f32x4 acc[4][4];
    #pragma unroll
    for (int m = 0; m < 4; ++m)
        #pragma unroll
        for (int nt = 0; nt < 4; ++nt)
            acc[m][nt] = (f32x4){0.f, 0.f, 0.f, 0.f};

    #pragma unroll
    for (int ks = 0; ks < 8; ++ks) {
        bf16x8 bfrag[4];
        #pragma unroll
        for (int nt = 0; nt < 4; ++nt)
            bfrag[nt] = *(const bf16x8*)&Bf[((size_t)(ks * 32 + w * 4 + nt) * 64 + l) * 8];
        bf16x8 afrag[4];
        #pragma unroll
        for (int m = 0; m < 4; ++m)
            afrag[m] = *(const bf16x8*)&A_lds[m * 16 + lrow][ks * 32 + lgrp * 8];
        #pragma unroll
        for (int m = 0; m < 4; ++m)
            #pragma unroll
            for (int nt = 0; nt < 4; ++nt)
                acc[m][nt] = __builtin_amdgcn_mfma_f32_16x16x32_bf16(
                    afrag[m], bfrag[nt], acc[m][nt], 0, 0, 0);
    }

    #pragma unroll
    for (int m = 0; m < 4; ++m)
        #pragma unroll
        for (int nt = 0; nt < 4; ++nt)
            #pragma unroll
            for (int r = 0; r < 4; ++r) {
                int row = b0 + m * 16 + lgrp * 4 + r;
                int n = (w * 4 + nt) * 16 + lrow;
                out[(size_t)row * 512 + n] = f2bf(acc[m][nt][r]);
            }
}

// ---------------------------------------------------------------------------
// Fallback: r8's verified direct simulation (used only if ws_size < 256 KB).
// ---------------------------------------------------------------------------
__global__ __launch_bounds__(256) void sim_kernel(
    const float* __restrict__ x, const float* __restrict__ theta,
    const float* __restrict__ omega, const float* __restrict__ attn_w,
    unsigned short* __restrict__ out)
{
    const int lane = threadIdx.x & 63;
    const int b = blockIdx.x * 4 + (threadIdx.x >> 6);

    int tgt[NQ];
    #pragma unroll
    for (int i = 0; i < NQ; ++i) {
        const float* row = attn_w + i * NQ;
        int best = 0; float bv = row[0];
        #pragma unroll
        for (int t2 = 1; t2 < NQ; ++t2) {
            float v = row[t2];
            if (v > bv) { bv = v; best = t2; }
        }
        tgt[i] = best;
    }

    float cq[NQ], sq[NQ];
    #pragma unroll
    for (int q = 0; q < NQ; ++q) {
        float a = 0.5f * x[(size_t)b * NQ + q];
        sincosf(a, &sq[q], &cq[q]);
    }
    float re[4], im[4];
    #pragma unroll
    for (int c = 0; c < 4; ++c) {
        int j = c * 64 + lane;
        float v = 1.0f;
        #pragma unroll
        for (int q = 0; q < NQ; ++q)
            v *= ((j >> (7 - q)) & 1) ? sq[q] : cq[q];
        re[c] = v; im[c] = 0.0f;
    }

    for (int layer = 0; layer < NL; ++layer) {
        #pragma unroll
        for (int q = 0; q < NQ; ++q) {
            float a = 0.5f * theta[layer * NQ + q];
            float s, cc; sincosf(a, &s, &cc);
            const int mask = 1 << (7 - q);
            if (mask == 128)      { RYPAIR(0, 2); RYPAIR(1, 3); }
            else if (mask == 64)  { RYPAIR(0, 1); RYPAIR(2, 3); }
            else {
                #pragma unroll
                for (int c = 0; c < 4; ++c) {
                    float pr = __shfl_xor(re[c], mask);
                    float pi = __shfl_xor(im[c], mask);
                    if (lane & mask) { re[c] = s * pr + cc * re[c]; im[c] = s * pi + cc * im[c]; }
                    else             { re[c] = cc * re[c] - s * pr; im[c] = cc * im[c] - s * pi; }
                }
            }
        }
        #pragma unroll
        for (int i = 0; i < NQ; ++i) {
            int t2 = tgt[i];
            if (t2 == i) continue;
            int cmask = 1 << (7 - i);
            int tmask = 1 << (7 - t2);
            if (tmask == 128) {
                int j0 = lane, j1 = 64 + lane, j2 = 128 + lane, j3 = 192 + lane;
                bool k0 = (j0 & cmask), k1 = (j1 & cmask), k2 = (j2 & cmask), k3 = (j3 & cmask);
                float n0r = k0 ? re[2] : re[0], n0i = k0 ? im[2] : im[0];
                float n1r = k1 ? re[3] : re[1], n1i = k1 ? im[3] : im[1];
                float n2r = k2 ? re[0] : re[2], n2i = k2 ? im[0] : im[2];
                float n3r = k3 ? re[1] : re[3], n3i = k3 ? im[1] : im[3];
                re[0] = n0r; im[0] = n0i; re[1] = n1r; im[1] = n1i;
                re[2] = n2r; im[2] = n2i; re[3] = n3r; im[3] = n3i;
            } else if (tmask == 64) {
                int j0 = lane, j1 = 64 + lane, j2 = 128 + lane, j3 = 192 + lane;
                bool k0 = (j0 & cmask), k1 = (j1 & cmask), k2 = (j2 & cmask), k3 = (j3 & cmask);
                float n0r = k0 ? re[1] : re[0], n0i = k0 ? im[1] : im[0];
                float n1r = k1 ? re[0] : re[1], n1i = k1 ? im[0] : im[1];
                float n2r = k2 ? re[3] : re[2], n2i = k2 ? im[3] : im[2];
                float n3r = k3 ? re[2] : re[3], n3i = k3 ? im[2] : im[3];
                re[0] = n0r; im[0] = n0i; re[1] = n1r; im[1] = n1i;
                re[2] = n2r; im[2] = n2i; re[3] = n3r; im[3] = n3i;
            } else {
                #pragma unroll
                for (int c = 0; c < 4; ++c) {
                    int j = c * 64 + lane;
                    float pr = __shfl_xor(re[c], tmask);
                    float pi = __shfl_xor(im[c], tmask);
                    bool take = (j & cmask) != 0;
                    re[c] = take ? pr : re[c];
                    im[c] = take ? pi : im[c];
                }
            }
        }
        #pragma unroll
        for (int q = 0; q < NQ; ++q) {
            float a = 0.5f * omega[layer * NQ + q];
            float sa, ca; sincosf(a, &sa, &ca);
            const int mask = 1 << (7 - q);
            #pragma unroll
            for (int c = 0; c < 4; ++c) {
                int j = c * 64 + lane;
                float sb = (j & mask) ? sa : -sa;
                float r2 = re[c] * ca - im[c] * sb;
                float i2 = re[c] * sb + im[c] * ca;
                re[c] = r2; im[c] = i2;
            }
        }
    }

    #pragma unroll
    for (int c = 0; c < 4; ++c) {
        size_t elem = (size_t)b * DIM + c * 64 + lane;
        unsigned int pack = (unsigned int)f2bf(im[c]) | ((unsigned int)f2bf(re[c]) << 16);
        *(unsigned int*)&out[elem * 2] = pack;
    }
}

extern "C" void kernel_launch(void* const* d_in, const int* in_sizes, int n_in,
                              void* d_out, int out_size, void* d_ws, size_t ws_size,
                              hipStream_t stream) {
    const float* x      = (const float*)d_in[0];
    const float* theta  = (const float*)d_in[1];
    const float* omega  = (const float*)d_in[2];
    const float* attn_w = (const float*)d_in[3];

    const size_t B_BYTES = (size_t)DIM * 512 * 2;   // 256 KB fragment-ordered B
    if (ws_size >= B_BYTES) {
        unsigned short* Bf = (unsigned short*)d_ws;
        build_B_kernel<<<DIM / 4, 256, 0, stream>>>(theta, omega, attn_w, Bf);
        gemm_kernel<<<BATCH / 64, 512, 0, stream>>>(x, Bf, (unsigned short*)d_out);
    } else {
        sim_kernel<<<BATCH / 4, 256, 0, stream>>>(x, theta, omega, attn_w,
                                                  (unsigned short*)d_out);
    }
}